// Round 1
// baseline (2926.231 us; speedup 1.0000x reference)
//
#include <hip/hip_runtime.h>

typedef unsigned short ushort_t;
typedef unsigned int uint32;

#define BATCH 1024
#define TCTX 32
#define DIN 512
#define DSAE 8192
#define KDIM 16384   // TCTX*DIN
#define KTOP 64

// ---- workspace layout (bytes) ----
// [0, 32MB)        x_bf16      16,777,216 ushort
// [32MB, 64MB)     pre         8,388,608 float
// [64MB, +256KB)   topv        1024*64 float
// [.. , +256KB)    topi        1024*64 int
// [.. , +64B)      loss accums 6 float
#define WS_XB   0
#define WS_PRE  33554432
#define WS_TOPV 67108864
#define WS_TOPI 67371008
#define WS_ACC  67633152

typedef __attribute__((ext_vector_type(4))) float f32x4;
typedef __attribute__((ext_vector_type(8))) short bf16x8;

__device__ __forceinline__ ushort_t f2bf(float f) {
  uint32 b = __float_as_uint(f);
  b += 0x7FFFu + ((b >> 16) & 1u);   // round-to-nearest-even
  return (ushort_t)(b >> 16);
}

__device__ __forceinline__ void async16(const void* g, void* l) {
  __builtin_amdgcn_global_load_lds(
      (const __attribute__((address_space(1))) uint32*)g,
      (__attribute__((address_space(3))) uint32*)l, 16, 0, 0);
}

// ---------------- init: zero loss accumulators ----------------
__global__ void init_acc(float* acc) {
  if (threadIdx.x < 8) acc[threadIdx.x] = 0.f;
}

// ---------------- convert x to bf16 ----------------
__global__ __launch_bounds__(256) void convert_x(const float* __restrict__ x,
                                                 ushort_t* __restrict__ xb) {
  size_t i = (size_t)blockIdx.x * 256 + threadIdx.x;   // handles 4 floats
  float4 v = ((const float4*)x)[i];
  uint32 lo = (uint32)f2bf(v.x) | ((uint32)f2bf(v.y) << 16);
  uint32 hi = (uint32)f2bf(v.z) | ((uint32)f2bf(v.w) << 16);
  ((uint2*)xb)[i] = make_uint2(lo, hi);
}

// ---------------- encoder GEMM: pre = x_bf16 @ W_enc + b_enc ----------------
// A: (1024 x 16384) bf16 row-major (K contiguous)  -> global_load_lds 16B
// B: (16384 x 8192) fp32 row-major (N contiguous)  -> scalar load + convert +
//    transpose into LDS [n][k] so fragment reads are contiguous ds_read_b128.
#define BM 128
#define BN 128
#define BK 32

__global__ __launch_bounds__(256) void gemm_enc(const ushort_t* __restrict__ Abf,
                                                const float* __restrict__ W,
                                                const float* __restrict__ benc,
                                                float* __restrict__ pre) {
  __shared__ ushort_t As[BM * BK];   // 8 KB, row r at r*BK (unpadded: global_load_lds)
  __shared__ ushort_t Bs[BN * BK];   // 8 KB, row n at n*BK

  const int tid = threadIdx.x;
  const int lane = tid & 63, w = tid >> 6;
  const int m0 = blockIdx.x * BM, n0 = blockIdx.y * BN;
  const int wm = w & 1, wn = w >> 1;

  f32x4 acc[4][4];
#pragma unroll
  for (int m = 0; m < 4; m++)
#pragma unroll
    for (int n = 0; n < 4; n++)
      acc[m][n] = (f32x4){0.f, 0.f, 0.f, 0.f};

  const int bn = tid >> 1;           // 0..127 : B column (n) this thread stages
  const int bkh = (tid & 1) << 4;    // 0 or 16 : which half of the k-range

  for (int kt = 0; kt < KDIM / BK; kt++) {
    const int k0 = kt * BK;
    // --- stage A via async global->LDS (16B per lane, lane-linear layout) ---
#pragma unroll
    for (int c = 0; c < 2; c++) {
      const int rbase = (w * 2 + c) * 16;
      const ushort_t* g = Abf + (size_t)(m0 + rbase + (lane >> 2)) * KDIM
                              + (k0 + (lane & 3) * 8);
      async16(g, (char*)As + (size_t)(w * 2 + c) * 1024);
    }
    // --- stage B: 16 scalar fp32 loads (k-major per thread), convert, 2x b128 write ---
    float bv[16];
#pragma unroll
    for (int i = 0; i < 16; i++)
      bv[i] = W[(size_t)(k0 + bkh + i) * DSAE + n0 + bn];
    bf16x8 p0, p1;
#pragma unroll
    for (int i = 0; i < 8; i++) {
      p0[i] = (short)f2bf(bv[i]);
      p1[i] = (short)f2bf(bv[i + 8]);
    }
    *(bf16x8*)&Bs[bn * BK + bkh] = p0;
    *(bf16x8*)&Bs[bn * BK + bkh + 8] = p1;

    __syncthreads();   // compiler drains vmcnt (async LDS DMA) + lgkm here

    bf16x8 af[4], bfr[4];
#pragma unroll
    for (int m = 0; m < 4; m++)
      af[m] = *(const bf16x8*)&As[(wm * 64 + m * 16 + (lane & 15)) * BK + (lane >> 4) * 8];
#pragma unroll
    for (int n = 0; n < 4; n++)
      bfr[n] = *(const bf16x8*)&Bs[(wn * 64 + n * 16 + (lane & 15)) * BK + (lane >> 4) * 8];
#pragma unroll
    for (int m = 0; m < 4; m++)
#pragma unroll
      for (int n = 0; n < 4; n++)
        acc[m][n] = __builtin_amdgcn_mfma_f32_16x16x32_bf16(af[m], bfr[n], acc[m][n], 0, 0, 0);

    __syncthreads();
  }

  // epilogue: C/D layout col=lane&15, row=(lane>>4)*4+reg
#pragma unroll
  for (int m = 0; m < 4; m++) {
    const int row = m0 + wm * 64 + m * 16 + (lane >> 4) * 4;
#pragma unroll
    for (int n = 0; n < 4; n++) {
      const int col = n0 + wn * 64 + n * 16 + (lane & 15);
      const float be = benc[col];
#pragma unroll
      for (int r = 0; r < 4; r++)
        pre[(size_t)(row + r) * DSAE + col] = acc[m][n][r] + be;
    }
  }
}

// ---------------- top-64 per row (iterative argmax in LDS) ----------------
__global__ __launch_bounds__(256) void topk_kernel(const float* __restrict__ pre,
                                                   float* __restrict__ topv,
                                                   int* __restrict__ topi) {
  __shared__ float sv[DSAE];   // 32 KB
  __shared__ float wvv[4];
  __shared__ int wvi[4];
  __shared__ float bwv;
  __shared__ int bwi;
  const int b = blockIdx.x, t = threadIdx.x;
  const float* row = pre + (size_t)b * DSAE;
#pragma unroll
  for (int i = 0; i < 32; i++) sv[t + 256 * i] = row[t + 256 * i];
  __syncthreads();

  float lv = -1e30f; int li = 0;
#pragma unroll
  for (int i = 0; i < 32; i++) {
    float v = sv[t + 256 * i];
    if (v > lv) { lv = v; li = t + 256 * i; }
  }
  const int lane = t & 63, wid = t >> 6;
  for (int it = 0; it < KTOP; it++) {
    float v = lv; int ii = li;
    for (int off = 32; off; off >>= 1) {
      float ov = __shfl_down(v, off);
      int oi = __shfl_down(ii, off);
      if (ov > v) { v = ov; ii = oi; }
    }
    if (lane == 0) { wvv[wid] = v; wvi[wid] = ii; }
    __syncthreads();
    if (t == 0) {
      float bv = wvv[0]; int bi = wvi[0];
      for (int j = 1; j < 4; j++)
        if (wvv[j] > bv) { bv = wvv[j]; bi = wvi[j]; }
      bwv = bv; bwi = bi;
      topv[b * KTOP + it] = bv;
      topi[b * KTOP + it] = bi;
    }
    __syncthreads();
    const int winner = bwi;
    if ((winner & 255) == t) {
      sv[winner] = -1e30f;
      lv = -1e30f; li = 0;
#pragma unroll
      for (int i = 0; i < 32; i++) {
        float vv = sv[t + 256 * i];
        if (vv > lv) { lv = vv; li = t + 256 * i; }
      }
    }
    __syncthreads();
  }
}

// ---------------- z output: zero + scatter relu(top-k) ----------------
__global__ void zero_z(float* z) {
  size_t i = (size_t)blockIdx.x * 256 + threadIdx.x;
  if (i < (size_t)BATCH * DSAE) z[i] = 0.f;
}

__global__ void scatter_z(const float* __restrict__ topv, const int* __restrict__ topi,
                          float* __restrict__ z) {
  const int b = blockIdx.x, t = threadIdx.x;   // 64 threads
  const float v = topv[b * KTOP + t];
  const int i = topi[b * KTOP + t];
  z[(size_t)b * DSAE + i] = fmaxf(v, 0.f);
}

// ---------------- sparse decode + SSE loss per scale ----------------
template <int NPER>
__global__ __launch_bounds__(256) void decode_kernel(
    const float* __restrict__ x, const float* __restrict__ Wd,
    const float* __restrict__ bd, const float* __restrict__ topv,
    const int* __restrict__ topi, float* __restrict__ xhat_out,
    float* __restrict__ loss_acc, int P, int elements, int start) {
  const int b = blockIdx.x;
  const int base = blockIdx.y * (NPER * 256);
  const int t = threadIdx.x;
  __shared__ float sval[KTOP];
  __shared__ int sidx[KTOP];
  if (t < KTOP) {
    sval[t] = fmaxf(topv[b * KTOP + t], 0.f);   // z = relu(vals)
    sidx[t] = topi[b * KTOP + t];
  }
  __syncthreads();

  float acc[NPER];
#pragma unroll
  for (int j = 0; j < NPER; j++) acc[j] = bd[base + t + (j << 8)];

  for (int k = 0; k < KTOP; k++) {
    const int idx = sidx[k];
    if (idx < P) {   // block-uniform branch
      const float v = sval[k];
      const float* wr = Wd + (size_t)idx * elements + base + t;
#pragma unroll
      for (int j = 0; j < NPER; j++) acc[j] = fmaf(v, wr[j << 8], acc[j]);
    }
  }

  const float* xc = x + (size_t)b * KDIM + start * DIN + base + t;
  float sse = 0.f;
#pragma unroll
  for (int j = 0; j < NPER; j++) {
    const float d = acc[j] - xc[j << 8];
    sse = fmaf(d, d, sse);
    if (xhat_out) xhat_out[(size_t)b * KDIM + base + t + (j << 8)] = acc[j];
  }
  for (int off = 32; off; off >>= 1) sse += __shfl_down(sse, off);
  __shared__ float ssw[4];
  const int lane = t & 63, wid = t >> 6;
  if (lane == 0) ssw[wid] = sse;
  __syncthreads();
  if (t == 0) atomicAdd(loss_acc, ssw[0] + ssw[1] + ssw[2] + ssw[3]);
}

// ---------------- finalize loss ----------------
__global__ void finalize(const float* __restrict__ acc, float* __restrict__ out0) {
  if (threadIdx.x == 0) {
    const float sdiv[6] = {1.f, 2.f, 4.f, 8.f, 16.f, 32.f};
    float s = 0.f;
    for (int i = 0; i < 6; i++) s += acc[i] / (1024.f * sdiv[i]);
    out0[0] = s / 6.f;
  }
}

extern "C" void kernel_launch(void* const* d_in, const int* in_sizes, int n_in,
                              void* d_out, int out_size, void* d_ws, size_t ws_size,
                              hipStream_t stream) {
  const float* x = (const float*)d_in[0];
  const float* W_enc = (const float*)d_in[1];
  const float* b_enc = (const float*)d_in[2];
  // dict order interleaves W_dec_i, b_dec_i
  const float* W_dec[6];
  const float* b_dec[6];
  for (int i = 0; i < 6; i++) {
    W_dec[i] = (const float*)d_in[3 + 2 * i];
    b_dec[i] = (const float*)d_in[4 + 2 * i];
  }
  float* out_loss = (float*)d_out;
  float* out_xhat = out_loss + 1;                       // (1024,32,512)
  float* out_z = out_xhat + (size_t)BATCH * KDIM;       // (1024,8192)

  char* ws = (char*)d_ws;
  ushort_t* xb = (ushort_t*)(ws + WS_XB);
  float* pre = (float*)(ws + WS_PRE);
  float* topv = (float*)(ws + WS_TOPV);
  int* topi = (int*)(ws + WS_TOPI);
  float* lacc = (float*)(ws + WS_ACC);

  init_acc<<<1, 64, 0, stream>>>(lacc);
  convert_x<<<16384, 256, 0, stream>>>(x, xb);
  gemm_enc<<<dim3(8, 64), 256, 0, stream>>>(xb, W_enc, b_enc, pre);
  topk_kernel<<<1024, 256, 0, stream>>>(pre, topv, topi);
  zero_z<<<32768, 256, 0, stream>>>(out_z);
  scatter_z<<<1024, 64, 0, stream>>>(topv, topi, out_z);

  // scale i: (P, elements=s*512, start=(32-s)/2); chunks = elements/(NPER*256)
  decode_kernel<2><<<dim3(1024, 1), 256, 0, stream>>>(x, W_dec[0], b_dec[0], topv, topi,
                                                      nullptr, lacc + 0, 1366, 512, 15);
  decode_kernel<4><<<dim3(1024, 1), 256, 0, stream>>>(x, W_dec[1], b_dec[1], topv, topi,
                                                      nullptr, lacc + 1, 2732, 1024, 15);
  decode_kernel<8><<<dim3(1024, 1), 256, 0, stream>>>(x, W_dec[2], b_dec[2], topv, topi,
                                                      nullptr, lacc + 2, 4097, 2048, 14);
  decode_kernel<16><<<dim3(1024, 1), 256, 0, stream>>>(x, W_dec[3], b_dec[3], topv, topi,
                                                       nullptr, lacc + 3, 5462, 4096, 12);
  decode_kernel<16><<<dim3(1024, 2), 256, 0, stream>>>(x, W_dec[4], b_dec[4], topv, topi,
                                                       nullptr, lacc + 4, 6827, 8192, 8);
  decode_kernel<16><<<dim3(1024, 4), 256, 0, stream>>>(x, W_dec[5], b_dec[5], topv, topi,
                                                       out_xhat, lacc + 5, 8192, 16384, 0);
  finalize<<<1, 64, 0, stream>>>(lacc, out_loss);
}